// Round 14
// baseline (281.248 us; speedup 1.0000x reference)
//
#include <hip/hip_runtime.h>
#include <math.h>

typedef __attribute__((ext_vector_type(8))) short short8;
typedef __bf16 bf16x8 __attribute__((ext_vector_type(8)));
typedef __attribute__((ext_vector_type(4))) float f32x4;
typedef __attribute__((ext_vector_type(16))) float f32x16;

__device__ inline short f2bf(float f) {
    unsigned u = __builtin_bit_cast(unsigned, f);
    u += 0x7fff + ((u >> 16) & 1);   // round-to-nearest-even
    return (short)(u >> 16);
}
__device__ inline float bf2f(short h) {
    return __builtin_bit_cast(float, ((unsigned)(unsigned short)h) << 16);
}
__device__ inline float gelu_f(float x) {
    return 0.5f * x * (1.f + erff(x * 0.70710678118654752f));
}

// ---------------------------------------------------------------------------
// Fused prep: input casts (blocks 0..6143) + all 6 weight transposes
// (blocks 6144..8191, all plain bf16 [N][K]). Block-uniform branches.
// ---------------------------------------------------------------------------
__global__ __launch_bounds__(256) void prep_all(
    const float* __restrict__ q, const float* __restrict__ k,
    const float* __restrict__ v,
    short* __restrict__ qc, short* __restrict__ kc, short* __restrict__ vc,
    const float* __restrict__ Wq1, const float* __restrict__ Wk1,
    const float* __restrict__ Wq2, const float* __restrict__ Wk2,
    const float* __restrict__ Wv,  const float* __restrict__ Wo,
    short* __restrict__ Wq1t, short* __restrict__ Wk1t,
    short* __restrict__ Wq2t, short* __restrict__ Wk2t,
    short* __restrict__ Wvt,  short* __restrict__ Wot)
{
    int id = blockIdx.x;
    if (id < 6144) {
        const float* src = id < 2048 ? q : (id < 4096 ? k : v);
        short* dst = id < 2048 ? qc : (id < 4096 ? kc : vc);
        int blk = id & 2047;
        size_t i = ((size_t)blk * 256 + threadIdx.x) * 8;
        float4 a = *(const float4*)(src + i);
        float4 b = *(const float4*)(src + i + 4);
        short8 o;
        o[0] = f2bf(a.x); o[1] = f2bf(a.y); o[2] = f2bf(a.z); o[3] = f2bf(a.w);
        o[4] = f2bf(b.x); o[5] = f2bf(b.y); o[6] = f2bf(b.z); o[7] = f2bf(b.w);
        *(short8*)(void*)(dst + i) = o;
        return;
    }
    id -= 6144;
    const float* W; short* Wt; int K, N;
    if (id < 512)       { W = Wq1; Wt = Wq1t; K = 512;  N = 1024; }
    else if (id < 1024) { W = Wk1; Wt = Wk1t; K = 512;  N = 1024; id -= 512; }
    else if (id < 1280) { W = Wq2; Wt = Wq2t; K = 1024; N = 256;  id -= 1024; }
    else if (id < 1536) { W = Wk2; Wt = Wk2t; K = 1024; N = 256;  id -= 1280; }
    else if (id < 1792) { W = Wv;  Wt = Wvt;  K = 512;  N = 512;  id -= 1536; }
    else                { W = Wo;  Wt = Wot;  K = 512;  N = 512;  id -= 1792; }
    int nx = N >> 5;
    int n0 = (id % nx) * 32, k0 = (id / nx) * 32;

    __shared__ float T[32][33];
    int tid = threadIdx.x;
    int r = tid >> 3, c4 = (tid & 7) * 4;
    float4 v4 = *(const float4*)&W[(size_t)(k0 + r) * N + n0 + c4];
    T[r][c4 + 0] = v4.x; T[r][c4 + 1] = v4.y; T[r][c4 + 2] = v4.z; T[r][c4 + 3] = v4.w;
    __syncthreads();
    short4 o;
    o.x = f2bf(T[c4 + 0][r]);
    o.y = f2bf(T[c4 + 1][r]);
    o.z = f2bf(T[c4 + 2][r]);
    o.w = f2bf(T[c4 + 3][r]);
    *(short4*)&Wt[(size_t)(n0 + r) * K + k0 + c4] = o;
}

// ---------------------------------------------------------------------------
// bf16 MFMA GEMM, B^T layout, BK=64, XCD-aware swizzle (proven R9).
// ---------------------------------------------------------------------------
template <int ACT, int OUTF32, int BN>
__global__ __launch_bounds__(256) void gemm_bt(
    const short* __restrict__ A0, const short* __restrict__ A1,
    const short* __restrict__ B0, const short* __restrict__ B1,
    const float* __restrict__ b0, const float* __restrict__ b1,
    void* C0_, void* C1_,
    float s0, float s1, int nbn, int N, int K)
{
    constexpr int NT = BN / 32;
    const int z = blockIdx.z;
    const short* A = z ? A1 : A0;
    const short* B = z ? B1 : B0;
    const float* bias = z ? b1 : b0;
    void* C_ = z ? C1_ : C0_;
    const float scale = z ? s1 : s0;

    const int L = blockIdx.x;
    const int xcd = L & 7;
    const int per = L >> 3;
    const int bn = (per % nbn) * BN;
    const int bm = ((per / nbn) * 8 + xcd) * 128;

    const int tid = threadIdx.x;
    const int w = tid >> 6;
    const int lane = tid & 63;
    const int l15 = lane & 15, quad = lane >> 4;
    const int wm = (w >> 1) * 64, wn = (w & 1) * (BN / 2);

    __shared__ __align__(16) short As[128 * 64];
    __shared__ __align__(16) short Bs[BN * 64];

    f32x4 acc[4][NT];
#pragma unroll
    for (int mt = 0; mt < 4; ++mt)
#pragma unroll
        for (int nt = 0; nt < NT; ++nt) acc[mt][nt] = (f32x4){0.f, 0.f, 0.f, 0.f};

    for (int k0 = 0; k0 < K; k0 += 64) {
#pragma unroll
        for (int i = 0; i < 4; ++i) {
            int ga = tid + i * 256;
            int row = ga >> 3, g = ga & 7;
            short8 aval = *(const short8*)(const void*)&A[(size_t)(bm + row) * K + k0 + g * 8];
            *(short8*)(void*)&As[row * 64 + ((g ^ (row & 7)) * 8)] = aval;
        }
#pragma unroll
        for (int i = 0; i < BN / 32; ++i) {
            int gb = tid + i * 256;
            int row = gb >> 3, g = gb & 7;
            short8 bval = *(const short8*)(const void*)&B[(size_t)(bn + row) * K + k0 + g * 8];
            *(short8*)(void*)&Bs[row * 64 + ((g ^ (row & 7)) * 8)] = bval;
        }
        __syncthreads();

#pragma unroll
        for (int ks = 0; ks < 2; ++ks) {
            bf16x8 af[4], bfr[NT];
#pragma unroll
            for (int t = 0; t < 4; ++t) {
                int row = wm + t * 16 + l15;
                af[t] = __builtin_bit_cast(bf16x8,
                    *(const short8*)(const void*)&As[row * 64 + (((ks * 4 + quad) ^ (row & 7)) * 8)]);
            }
#pragma unroll
            for (int t = 0; t < NT; ++t) {
                int row = wn + t * 16 + l15;
                bfr[t] = __builtin_bit_cast(bf16x8,
                    *(const short8*)(const void*)&Bs[row * 64 + (((ks * 4 + quad) ^ (row & 7)) * 8)]);
            }
#pragma unroll
            for (int mt = 0; mt < 4; ++mt)
#pragma unroll
                for (int nt = 0; nt < NT; ++nt)
                    acc[mt][nt] = __builtin_amdgcn_mfma_f32_16x16x32_bf16(af[mt], bfr[nt], acc[mt][nt], 0, 0, 0);
        }
        __syncthreads();
    }

    float bv[NT];
#pragma unroll
    for (int nt = 0; nt < NT; ++nt) bv[nt] = bias[bn + wn + nt * 16 + l15];
#pragma unroll
    for (int mt = 0; mt < 4; ++mt)
#pragma unroll
        for (int r = 0; r < 4; ++r) {
            int row = bm + wm + mt * 16 + quad * 4 + r;
#pragma unroll
            for (int nt = 0; nt < NT; ++nt) {
                float v = acc[mt][nt][r] + bv[nt];
                if (ACT) v = gelu_f(v);
                v *= scale;
                int col = bn + wn + nt * 16 + l15;
                if (OUTF32) ((float*)C_)[(size_t)row * N + col] = v;
                else        ((short*)C_)[(size_t)row * N + col] = f2bf(v);
            }
        }
}

// ---------------------------------------------------------------------------
// Fused K+V repack (one dispatch). y < 16: K-repack; y >= 16: V-repack.
// Layouts proven R5.
// ---------------------------------------------------------------------------
__global__ __launch_bounds__(256) void repack_kv(
    const short* __restrict__ kb, short* __restrict__ kfr,
    const short* __restrict__ vbb, short* __restrict__ vfr)
{
    const int kt = blockIdx.x;
    const int y = blockIdx.y;
    const int t = threadIdx.x;
    __shared__ short Vt[64][72];   // [key][dk] (V path only)

    if (y < 16) {
        const int bh = y;
        const int b = bh >> 3, h = bh & 7;
        const int c = t >> 6, l = t & 63;
        const int nt = c >> 1, ks = c & 1;
        int key = kt * 64 + nt * 32 + (l & 31);
        int k = ks * 16 + (l >> 5) * 8;
        short8 v = *(const short8*)(const void*)&kb[(size_t)(b * 4096 + key) * 256 + h * 32 + k];
        *(short8*)(void*)&kfr[((((size_t)bh * 64 + kt) * 4 + c) * 64 + l) * 8] = v;
        return;
    }
    const int bh = y - 16;
    const int b = bh >> 3, h = bh & 7;
#pragma unroll
    for (int it = 0; it < 2; ++it) {
        int idx = t + it * 256;
        int keyr = idx >> 3, c8 = (idx & 7) * 8;
        *(short8*)(void*)&Vt[keyr][c8] =
            *(const short8*)(const void*)&vbb[(size_t)(b * 4096 + kt * 64 + keyr) * 512 + h * 64 + c8];
    }
    __syncthreads();
#pragma unroll
    for (int it = 0; it < 2; ++it) {
        int chunk = (t >> 6) * 2 + it;
        int l = t & 63;
        int dt = chunk >> 2, ks = chunk & 3;
        short8 o;
#pragma unroll
        for (int j = 0; j < 8; ++j)
            o[j] = Vt[ks * 16 + (l >> 5) * 8 + j][dt * 32 + (l & 31)];
        *(short8*)(void*)&vfr[((((size_t)bh * 64 + kt) * 8 + chunk) * 64 + l) * 8] = o;
    }
}

// ---------------------------------------------------------------------------
// Flash attention (R13 structure: 4-wave blocks, waves=(q-group,key-half),
// l via MFMA, plain bf16 output) + restored next-K prefetch (R9-proven):
// kn for tile t+1 issued right after QK consumes kc, hiding the L2 latency
// that was the exposed stall at the loop head.
// ---------------------------------------------------------------------------
__global__ __launch_bounds__(256) void flash_ks(
    const short* __restrict__ qb, const short* __restrict__ kfr,
    const short* __restrict__ vfr, short* __restrict__ xbb)
{
    const int L = blockIdx.x;          // 0..1023
    const int xcd = L & 7;
    const int idx = L >> 3;            // 0..127
    const int bh = xcd * 2 + (idx & 1);
    const int qt = idx >> 1;           // 0..63: 64 q rows per block
    const int b = bh >> 3, h = bh & 7;
    const int w = threadIdx.x >> 6;
    const int qg = w >> 1;             // q-group 0/1 (32 rows each)
    const int kh = w & 1;              // key-half 0/1
    const int lane = threadIdx.x & 63;
    const int l31 = lane & 31;
    const int half = lane >> 5;

    // Pbuf: 4 x [32 q][64 key + 8 pad] bf16 = 18432 B; end-combine overlays.
    __shared__ __align__(16) char smem[18432];
    short* Pw = (short*)smem + w * 2304;

    const short* qrow = qb + (size_t)(b * 4096 + qt * 64 + qg * 32 + l31) * 256 + h * 32 + half * 8;
    bf16x8 qf0 = __builtin_bit_cast(bf16x8, *(const short8*)(const void*)qrow);
    bf16x8 qf1 = __builtin_bit_cast(bf16x8, *(const short8*)(const void*)(qrow + 16));

    // all-ones bf16 B-operand fragment (for l = P x ones)
    short8 ones_s;
#pragma unroll
    for (int j = 0; j < 8; ++j) ones_s[j] = (short)0x3F80;
    const bf16x8 onesf = __builtin_bit_cast(bf16x8, ones_s);

    f32x16 O0{}, O1{}, lacc{};

    const short* kbase = kfr + ((size_t)bh * 64) * 4 * 512 + lane * 8;
    const short* vbase = vfr + ((size_t)bh * 64) * 8 * 512 + lane * 8;

    // preload K for first tile
    bf16x8 kc[4], kn[4];
    {
        const short* kp = kbase + (size_t)(kh * 32) * 4 * 512;
#pragma unroll
        for (int c = 0; c < 4; ++c)
            kc[c] = __builtin_bit_cast(bf16x8, *(const short8*)(const void*)(kp + c * 512));
    }

#pragma unroll 1
    for (int t = 0; t < 32; ++t) {
        const int kt = kh * 32 + t;
        // V loads issued now, consumed after QK+exp (~300 cyc of cover)
        bf16x8 vc[8];
        const short* vp = vbase + (size_t)kt * 8 * 512;
#pragma unroll
        for (int c = 0; c < 8; ++c)
            vc[c] = __builtin_bit_cast(bf16x8, *(const short8*)(const void*)(vp + c * 512));

        f32x16 zero{};
        f32x16 s0 = __builtin_amdgcn_mfma_f32_32x32x16_bf16(kc[0], qf0, zero, 0, 0, 0);
        s0 = __builtin_amdgcn_mfma_f32_32x32x16_bf16(kc[1], qf1, s0, 0, 0, 0);
        f32x16 s1 = __builtin_amdgcn_mfma_f32_32x32x16_bf16(kc[2], qf0, zero, 0, 0, 0);
        s1 = __builtin_amdgcn_mfma_f32_32x32x16_bf16(kc[3], qf1, s1, 0, 0, 0);

        // kc consumed -> prefetch next tile's K (completes during exp+PV)
        if (t < 31) {
            const short* kp = kbase + (size_t)(kt + 1) * 4 * 512;
#pragma unroll
            for (int c = 0; c < 4; ++c)
                kn[c] = __builtin_bit_cast(bf16x8, *(const short8*)(const void*)(kp + c * 512));
        }

        // exp + truncation-pack P -> LDS (l handled by MFMA)
#pragma unroll
        for (int nt = 0; nt < 2; ++nt) {
            const f32x16& s = nt ? s1 : s0;
#pragma unroll
            for (int r2 = 0; r2 < 4; ++r2) {
                float p0 = __builtin_amdgcn_exp2f(s[r2 * 4 + 0]);
                float p1 = __builtin_amdgcn_exp2f(s[r2 * 4 + 1]);
                float p2 = __builtin_amdgcn_exp2f(s[r2 * 4 + 2]);
                float p3 = __builtin_amdgcn_exp2f(s[r2 * 4 + 3]);
                unsigned pk01 = __builtin_amdgcn_perm(
                    __builtin_bit_cast(unsigned, p1), __builtin_bit_cast(unsigned, p0), 0x07060302u);
                unsigned pk23 = __builtin_amdgcn_perm(
                    __builtin_bit_cast(unsigned, p3), __builtin_bit_cast(unsigned, p2), 0x07060302u);
                int2 pk; pk.x = (int)pk01; pk.y = (int)pk23;
                *(int2*)(void*)&Pw[l31 * 72 + nt * 32 + r2 * 8 + half * 4] = pk;
            }
        }

        bf16x8 pf[4];
#pragma unroll
        for (int ks = 0; ks < 4; ++ks)
            pf[ks] = __builtin_bit_cast(bf16x8,
                *(const short8*)(const void*)&Pw[l31 * 72 + ks * 16 + half * 8]);
#pragma unroll
        for (int ks = 0; ks < 4; ++ks) {
            O0 = __builtin_amdgcn_mfma_f32_32x32x16_bf16(pf[ks], vc[ks], O0, 0, 0, 0);
            O1 = __builtin_amdgcn_mfma_f32_32x32x16_bf16(pf[ks], vc[4 + ks], O1, 0, 0, 0);
            lacc = __builtin_amdgcn_mfma_f32_32x32x16_bf16(pf[ks], onesf, lacc, 0, 0, 0);
        }

#pragma unroll
        for (int c = 0; c < 4; ++c) kc[c] = kn[c];
    }

    // ---- combine key-half pairs per q-group (overlay on dead Pbuf) ----
    __syncthreads();   // all waves done with Pbuf
    float* redO = (float*)smem;              // [qg][32 q][66] = 16896 B
    float* redl = (float*)(smem + 16896);    // [qg*2+kh][32 q] = 512 B
    if (l31 == 0) {
#pragma unroll
        for (int r = 0; r < 16; ++r) {
            int q = (r & 3) + 8 * (r >> 2) + 4 * half;
            redl[(qg * 2 + kh) * 32 + q] = lacc[r];
        }
    }
    if (kh == 1) {
        float* Bo = redO + qg * 32 * 66;
#pragma unroll
        for (int r = 0; r < 16; ++r) {
            int q = (r & 3) + 8 * (r >> 2) + 4 * half;
            Bo[q * 66 + l31] = O0[r];
            Bo[q * 66 + 32 + l31] = O1[r];
        }
    }
    __syncthreads();
    if (kh == 0) {
        const float* Bo = redO + qg * 32 * 66;
#pragma unroll
        for (int r = 0; r < 16; ++r) {
            int q = (r & 3) + 8 * (r >> 2) + 4 * half;
            float o0 = O0[r] + Bo[q * 66 + l31];
            float o1 = O1[r] + Bo[q * 66 + 32 + l31];
            float inv = 1.f / (redl[(qg * 2 + 0) * 32 + q] + redl[(qg * 2 + 1) * 32 + q]);
            size_t row = (size_t)(b * 4096 + qt * 64 + qg * 32 + q);
            short* d = xbb + row * 512 + h * 64 + l31;
            d[0] = f2bf(o0 * inv);
            d[32] = f2bf(o1 * inv);
        }
    }
}

// ---------------------------------------------------------------------------
extern "C" void kernel_launch(void* const* d_in, const int* in_sizes, int n_in,
                              void* d_out, int out_size, void* d_ws, size_t ws_size,
                              hipStream_t stream)
{
    const float* query = (const float*)d_in[0];
    const float* key   = (const float*)d_in[1];
    const float* value = (const float*)d_in[2];
    const float* Wq1   = (const float*)d_in[3];
    const float* bq1   = (const float*)d_in[4];
    const float* Wq2   = (const float*)d_in[5];
    const float* bq2   = (const float*)d_in[6];
    const float* Wk1   = (const float*)d_in[7];
    const float* bk1   = (const float*)d_in[8];
    const float* Wk2   = (const float*)d_in[9];
    const float* bk2   = (const float*)d_in[10];
    const float* Wv    = (const float*)d_in[11];
    const float* bv    = (const float*)d_in[12];
    const float* Wo    = (const float*)d_in[13];
    const float* bo    = (const float*)d_in[14];
    float* out = (float*)d_out;

    // Workspace (bytes), overlays (proven R13):
    char* ws = (char*)d_ws;
    short* H1q   = (short*)(ws + 0);
    short* H1k   = (short*)(ws + 16777216);
    short* xbb   = (short*)(ws + 0);
    short* qcast = (short*)(ws + 33554432);
    short* kcast = (short*)(ws + 41943040);
    short* vcast = (short*)(ws + 50331648);
    short* qbb   = (short*)(ws + 33554432);
    short* kbb   = (short*)(ws + 37748736);
    short* vbb   = (short*)(ws + 41943040);
    short* kfr   = (short*)(ws + 50331648);
    short* vfr   = (short*)(ws + 54525952);
    short* Wq1t  = (short*)(ws + 62914560);
    short* Wk1t  = (short*)(ws + 63963136);
    short* Wq2t  = (short*)(ws + 65011712);
    short* Wk2t  = (short*)(ws + 65536000);
    short* Wvt   = (short*)(ws + 66060288);
    short* Wot   = (short*)(ws + 66584576);   // 512 KB -> end 67,108,864

    dim3 blk(256);
    const float qscale = 0.17677669529663687f * 1.4426950408889634f;

    // fused input casts + weight prep (one dispatch)
    prep_all<<<dim3(8192), blk, 0, stream>>>(
        query, key, value, qcast, kcast, vcast,
        Wq1, Wk1, Wq2, Wk2, Wv, Wo, Wq1t, Wk1t, Wq2t, Wk2t, Wvt, Wot);

    // MLP layer 1 (q & k batched): GELU, bf16. N=1024, K=512, BN=128, nbn=8
    gemm_bt<1, 0, 128><<<dim3(8 * 64, 1, 2), blk, 0, stream>>>(
        qcast, kcast, Wq1t, Wk1t, bq1, bk1, H1q, H1k, 1.f, 1.f, 8, 1024, 512);
    // MLP layer 2 (q & k batched): q pre-scaled. N=256, K=1024, BN=64, nbn=4
    gemm_bt<0, 0, 64><<<dim3(4 * 64, 1, 2), blk, 0, stream>>>(
        H1q, H1k, Wq2t, Wk2t, bq2, bk2, qbb, kbb, qscale, 1.f, 4, 256, 1024);
    // v projection: N=512, K=512, BN=64, nbn=8
    gemm_bt<0, 0, 64><<<dim3(8 * 64, 1, 1), blk, 0, stream>>>(
        vcast, vcast, Wvt, Wvt, bv, bv, vbb, vbb, 1.f, 1.f, 8, 512, 512);
    // fused frag-major repacks (one dispatch)
    repack_kv<<<dim3(64, 32), blk, 0, stream>>>(kbb, kfr, vbb, vfr);
    // attention: 4-wave blocks, l via MFMA, next-K prefetch, bf16 output
    flash_ks<<<dim3(1024), blk, 0, stream>>>(qbb, kfr, vfr, xbb);
    // output projection, plain bf16 (K=512) -> f32, BN=64, nbn=8
    gemm_bt<0, 1, 64><<<dim3(8 * 64, 1, 1), blk, 0, stream>>>(
        xbb, xbb, Wot, Wot, bo, bo, out, out, 1.f, 1.f, 8, 512, 512);
}

// Round 15
// 271.705 us; speedup vs baseline: 1.0351x; 1.0351x over previous
//
#include <hip/hip_runtime.h>
#include <math.h>

typedef __attribute__((ext_vector_type(8))) short short8;
typedef __bf16 bf16x8 __attribute__((ext_vector_type(8)));
typedef __attribute__((ext_vector_type(4))) float f32x4;
typedef __attribute__((ext_vector_type(16))) float f32x16;

__device__ inline short f2bf(float f) {
    unsigned u = __builtin_bit_cast(unsigned, f);
    u += 0x7fff + ((u >> 16) & 1);   // round-to-nearest-even
    return (short)(u >> 16);
}
__device__ inline float bf2f(short h) {
    return __builtin_bit_cast(float, ((unsigned)(unsigned short)h) << 16);
}
__device__ inline float gelu_f(float x) {
    return 0.5f * x * (1.f + erff(x * 0.70710678118654752f));
}

// ---------------------------------------------------------------------------
// Fused prep: input casts (blocks 0..6143) + all 6 weight transposes
// (blocks 6144..8191, all plain bf16 [N][K]). Block-uniform branches.
// ---------------------------------------------------------------------------
__global__ __launch_bounds__(256) void prep_all(
    const float* __restrict__ q, const float* __restrict__ k,
    const float* __restrict__ v,
    short* __restrict__ qc, short* __restrict__ kc, short* __restrict__ vc,
    const float* __restrict__ Wq1, const float* __restrict__ Wk1,
    const float* __restrict__ Wq2, const float* __restrict__ Wk2,
    const float* __restrict__ Wv,  const float* __restrict__ Wo,
    short* __restrict__ Wq1t, short* __restrict__ Wk1t,
    short* __restrict__ Wq2t, short* __restrict__ Wk2t,
    short* __restrict__ Wvt,  short* __restrict__ Wot)
{
    int id = blockIdx.x;
    if (id < 6144) {
        const float* src = id < 2048 ? q : (id < 4096 ? k : v);
        short* dst = id < 2048 ? qc : (id < 4096 ? kc : vc);
        int blk = id & 2047;
        size_t i = ((size_t)blk * 256 + threadIdx.x) * 8;
        float4 a = *(const float4*)(src + i);
        float4 b = *(const float4*)(src + i + 4);
        short8 o;
        o[0] = f2bf(a.x); o[1] = f2bf(a.y); o[2] = f2bf(a.z); o[3] = f2bf(a.w);
        o[4] = f2bf(b.x); o[5] = f2bf(b.y); o[6] = f2bf(b.z); o[7] = f2bf(b.w);
        *(short8*)(void*)(dst + i) = o;
        return;
    }
    id -= 6144;
    const float* W; short* Wt; int K, N;
    if (id < 512)       { W = Wq1; Wt = Wq1t; K = 512;  N = 1024; }
    else if (id < 1024) { W = Wk1; Wt = Wk1t; K = 512;  N = 1024; id -= 512; }
    else if (id < 1280) { W = Wq2; Wt = Wq2t; K = 1024; N = 256;  id -= 1024; }
    else if (id < 1536) { W = Wk2; Wt = Wk2t; K = 1024; N = 256;  id -= 1280; }
    else if (id < 1792) { W = Wv;  Wt = Wvt;  K = 512;  N = 512;  id -= 1536; }
    else                { W = Wo;  Wt = Wot;  K = 512;  N = 512;  id -= 1792; }
    int nx = N >> 5;
    int n0 = (id % nx) * 32, k0 = (id / nx) * 32;

    __shared__ float T[32][33];
    int tid = threadIdx.x;
    int r = tid >> 3, c4 = (tid & 7) * 4;
    float4 v4 = *(const float4*)&W[(size_t)(k0 + r) * N + n0 + c4];
    T[r][c4 + 0] = v4.x; T[r][c4 + 1] = v4.y; T[r][c4 + 2] = v4.z; T[r][c4 + 3] = v4.w;
    __syncthreads();
    short4 o;
    o.x = f2bf(T[c4 + 0][r]);
    o.y = f2bf(T[c4 + 1][r]);
    o.z = f2bf(T[c4 + 2][r]);
    o.w = f2bf(T[c4 + 3][r]);
    *(short4*)&Wt[(size_t)(n0 + r) * K + k0 + c4] = o;
}

// ---------------------------------------------------------------------------
// bf16 MFMA GEMM, B^T layout, BK=64, XCD-aware swizzle. BM/BN templated:
// BM=128/BN=128 for big GEMMs; BM=64/BN=64 doubles the grid for small-N
// GEMMs (4 blocks/CU = 16 waves/CU, vs 2 blocks/CU at BM=128).
// 4 waves in 2x2; each wave covers BM/2 x BN/2.
// ---------------------------------------------------------------------------
template <int ACT, int OUTF32, int BM, int BN>
__global__ __launch_bounds__(256) void gemm_bt(
    const short* __restrict__ A0, const short* __restrict__ A1,
    const short* __restrict__ B0, const short* __restrict__ B1,
    const float* __restrict__ b0, const float* __restrict__ b1,
    void* C0_, void* C1_,
    float s0, float s1, int nbn, int N, int K)
{
    constexpr int MT = BM / 32;        // m-tiles per wave
    constexpr int NT = BN / 32;        // n-tiles per wave
    const int z = blockIdx.z;
    const short* A = z ? A1 : A0;
    const short* B = z ? B1 : B0;
    const float* bias = z ? b1 : b0;
    void* C_ = z ? C1_ : C0_;
    const float scale = z ? s1 : s0;

    const int L = blockIdx.x;
    const int xcd = L & 7;
    const int per = L >> 3;
    const int bn = (per % nbn) * BN;
    const int bm = ((per / nbn) * 8 + xcd) * BM;

    const int tid = threadIdx.x;
    const int w = tid >> 6;
    const int lane = tid & 63;
    const int l15 = lane & 15, quad = lane >> 4;
    const int wm = (w >> 1) * (BM / 2), wn = (w & 1) * (BN / 2);

    __shared__ __align__(16) short As[BM * 64];
    __shared__ __align__(16) short Bs[BN * 64];

    f32x4 acc[MT][NT];
#pragma unroll
    for (int mt = 0; mt < MT; ++mt)
#pragma unroll
        for (int nt = 0; nt < NT; ++nt) acc[mt][nt] = (f32x4){0.f, 0.f, 0.f, 0.f};

    for (int k0 = 0; k0 < K; k0 += 64) {
#pragma unroll
        for (int i = 0; i < BM / 32; ++i) {
            int ga = tid + i * 256;
            int row = ga >> 3, g = ga & 7;
            short8 aval = *(const short8*)(const void*)&A[(size_t)(bm + row) * K + k0 + g * 8];
            *(short8*)(void*)&As[row * 64 + ((g ^ (row & 7)) * 8)] = aval;
        }
#pragma unroll
        for (int i = 0; i < BN / 32; ++i) {
            int gb = tid + i * 256;
            int row = gb >> 3, g = gb & 7;
            short8 bval = *(const short8*)(const void*)&B[(size_t)(bn + row) * K + k0 + g * 8];
            *(short8*)(void*)&Bs[row * 64 + ((g ^ (row & 7)) * 8)] = bval;
        }
        __syncthreads();

#pragma unroll
        for (int ks = 0; ks < 2; ++ks) {
            bf16x8 af[MT], bfr[NT];
#pragma unroll
            for (int t = 0; t < MT; ++t) {
                int row = wm + t * 16 + l15;
                af[t] = __builtin_bit_cast(bf16x8,
                    *(const short8*)(const void*)&As[row * 64 + (((ks * 4 + quad) ^ (row & 7)) * 8)]);
            }
#pragma unroll
            for (int t = 0; t < NT; ++t) {
                int row = wn + t * 16 + l15;
                bfr[t] = __builtin_bit_cast(bf16x8,
                    *(const short8*)(const void*)&Bs[row * 64 + (((ks * 4 + quad) ^ (row & 7)) * 8)]);
            }
#pragma unroll
            for (int mt = 0; mt < MT; ++mt)
#pragma unroll
                for (int nt = 0; nt < NT; ++nt)
                    acc[mt][nt] = __builtin_amdgcn_mfma_f32_16x16x32_bf16(af[mt], bfr[nt], acc[mt][nt], 0, 0, 0);
        }
        __syncthreads();
    }

    float bv[NT];
#pragma unroll
    for (int nt = 0; nt < NT; ++nt) bv[nt] = bias[bn + wn + nt * 16 + l15];
#pragma unroll
    for (int mt = 0; mt < MT; ++mt)
#pragma unroll
        for (int r = 0; r < 4; ++r) {
            int row = bm + wm + mt * 16 + quad * 4 + r;
#pragma unroll
            for (int nt = 0; nt < NT; ++nt) {
                float v = acc[mt][nt][r] + bv[nt];
                if (ACT) v = gelu_f(v);
                v *= scale;
                int col = bn + wn + nt * 16 + l15;
                if (OUTF32) ((float*)C_)[(size_t)row * N + col] = v;
                else        ((short*)C_)[(size_t)row * N + col] = f2bf(v);
            }
        }
}

// ---------------------------------------------------------------------------
// Fused K+V repack (proven R14). y < 16: K-repack; y >= 16: V-repack.
// ---------------------------------------------------------------------------
__global__ __launch_bounds__(256) void repack_kv(
    const short* __restrict__ kb, short* __restrict__ kfr,
    const short* __restrict__ vbb, short* __restrict__ vfr)
{
    const int kt = blockIdx.x;
    const int y = blockIdx.y;
    const int t = threadIdx.x;
    __shared__ short Vt[64][72];   // [key][dk] (V path only)

    if (y < 16) {
        const int bh = y;
        const int b = bh >> 3, h = bh & 7;
        const int c = t >> 6, l = t & 63;
        const int nt = c >> 1, ks = c & 1;
        int key = kt * 64 + nt * 32 + (l & 31);
        int k = ks * 16 + (l >> 5) * 8;
        short8 v = *(const short8*)(const void*)&kb[(size_t)(b * 4096 + key) * 256 + h * 32 + k];
        *(short8*)(void*)&kfr[((((size_t)bh * 64 + kt) * 4 + c) * 64 + l) * 8] = v;
        return;
    }
    const int bh = y - 16;
    const int b = bh >> 3, h = bh & 7;
#pragma unroll
    for (int it = 0; it < 2; ++it) {
        int idx = t + it * 256;
        int keyr = idx >> 3, c8 = (idx & 7) * 8;
        *(short8*)(void*)&Vt[keyr][c8] =
            *(const short8*)(const void*)&vbb[(size_t)(b * 4096 + kt * 64 + keyr) * 512 + h * 64 + c8];
    }
    __syncthreads();
#pragma unroll
    for (int it = 0; it < 2; ++it) {
        int chunk = (t >> 6) * 2 + it;
        int l = t & 63;
        int dt = chunk >> 2, ks = chunk & 3;
        short8 o;
#pragma unroll
        for (int j = 0; j < 8; ++j)
            o[j] = Vt[ks * 16 + (l >> 5) * 8 + j][dt * 32 + (l & 31)];
        *(short8*)(void*)&vfr[((((size_t)bh * 64 + kt) * 8 + chunk) * 64 + l) * 8] = o;
    }
}

// ---------------------------------------------------------------------------
// Flash attention — R13 proven form, verbatim (no prefetch: R14 showed the
// +16 VGPR and kc=kn movs cost more than the hidden latency). 4-wave blocks,
// waves=(q-group,key-half), l via MFMA (P x ones), perm-truncation P pack,
// plain bf16 output, XCD-pinned grid 1024.
// ---------------------------------------------------------------------------
__global__ __launch_bounds__(256) void flash_ks(
    const short* __restrict__ qb, const short* __restrict__ kfr,
    const short* __restrict__ vfr, short* __restrict__ xbb)
{
    const int L = blockIdx.x;          // 0..1023
    const int xcd = L & 7;
    const int idx = L >> 3;            // 0..127
    const int bh = xcd * 2 + (idx & 1);
    const int qt = idx >> 1;           // 0..63: 64 q rows per block
    const int b = bh >> 3, h = bh & 7;
    const int w = threadIdx.x >> 6;
    const int qg = w >> 1;             // q-group 0/1 (32 rows each)
    const int kh = w & 1;              // key-half 0/1
    const int lane = threadIdx.x & 63;
    const int l31 = lane & 31;
    const int half = lane >> 5;

    // Pbuf: 4 x [32 q][64 key + 8 pad] bf16 = 18432 B; end-combine overlays.
    __shared__ __align__(16) char smem[18432];
    short* Pw = (short*)smem + w * 2304;

    const short* qrow = qb + (size_t)(b * 4096 + qt * 64 + qg * 32 + l31) * 256 + h * 32 + half * 8;
    bf16x8 qf0 = __builtin_bit_cast(bf16x8, *(const short8*)(const void*)qrow);
    bf16x8 qf1 = __builtin_bit_cast(bf16x8, *(const short8*)(const void*)(qrow + 16));

    // all-ones bf16 B-operand fragment (for l = P x ones)
    short8 ones_s;
#pragma unroll
    for (int j = 0; j < 8; ++j) ones_s[j] = (short)0x3F80;
    const bf16x8 onesf = __builtin_bit_cast(bf16x8, ones_s);

    f32x16 O0{}, O1{}, lacc{};

    const short* kbase = kfr + ((size_t)bh * 64) * 4 * 512 + lane * 8;
    const short* vbase = vfr + ((size_t)bh * 64) * 8 * 512 + lane * 8;

#pragma unroll 1
    for (int t = 0; t < 32; ++t) {
        const int kt = kh * 32 + t;
        bf16x8 kc[4], vc[8];
        const short* kp = kbase + (size_t)kt * 4 * 512;
        const short* vp = vbase + (size_t)kt * 8 * 512;
#pragma unroll
        for (int c = 0; c < 4; ++c)
            kc[c] = __builtin_bit_cast(bf16x8, *(const short8*)(const void*)(kp + c * 512));
#pragma unroll
        for (int c = 0; c < 8; ++c)
            vc[c] = __builtin_bit_cast(bf16x8, *(const short8*)(const void*)(vp + c * 512));

        f32x16 zero{};
        f32x16 s0 = __builtin_amdgcn_mfma_f32_32x32x16_bf16(kc[0], qf0, zero, 0, 0, 0);
        s0 = __builtin_amdgcn_mfma_f32_32x32x16_bf16(kc[1], qf1, s0, 0, 0, 0);
        f32x16 s1 = __builtin_amdgcn_mfma_f32_32x32x16_bf16(kc[2], qf0, zero, 0, 0, 0);
        s1 = __builtin_amdgcn_mfma_f32_32x32x16_bf16(kc[3], qf1, s1, 0, 0, 0);

        // exp + truncation-pack P -> LDS (l handled by MFMA)
#pragma unroll
        for (int nt = 0; nt < 2; ++nt) {
            const f32x16& s = nt ? s1 : s0;
#pragma unroll
            for (int r2 = 0; r2 < 4; ++r2) {
                float p0 = __builtin_amdgcn_exp2f(s[r2 * 4 + 0]);
                float p1 = __builtin_amdgcn_exp2f(s[r2 * 4 + 1]);
                float p2 = __builtin_amdgcn_exp2f(s[r2 * 4 + 2]);
                float p3 = __builtin_amdgcn_exp2f(s[r2 * 4 + 3]);
                unsigned pk01 = __builtin_amdgcn_perm(
                    __builtin_bit_cast(unsigned, p1), __builtin_bit_cast(unsigned, p0), 0x07060302u);
                unsigned pk23 = __builtin_amdgcn_perm(
                    __builtin_bit_cast(unsigned, p3), __builtin_bit_cast(unsigned, p2), 0x07060302u);
                int2 pk; pk.x = (int)pk01; pk.y = (int)pk23;
                *(int2*)(void*)&Pw[l31 * 72 + nt * 32 + r2 * 8 + half * 4] = pk;
            }
        }

        bf16x8 pf[4];
#pragma unroll
        for (int ks = 0; ks < 4; ++ks)
            pf[ks] = __builtin_bit_cast(bf16x8,
                *(const short8*)(const void*)&Pw[l31 * 72 + ks * 16 + half * 8]);
#pragma unroll
        for (int ks = 0; ks < 4; ++ks) {
            O0 = __builtin_amdgcn_mfma_f32_32x32x16_bf16(pf[ks], vc[ks], O0, 0, 0, 0);
            O1 = __builtin_amdgcn_mfma_f32_32x32x16_bf16(pf[ks], vc[4 + ks], O1, 0, 0, 0);
            lacc = __builtin_amdgcn_mfma_f32_32x32x16_bf16(pf[ks], onesf, lacc, 0, 0, 0);
        }
    }

    // ---- combine key-half pairs per q-group (overlay on dead Pbuf) ----
    __syncthreads();   // all waves done with Pbuf
    float* redO = (float*)smem;              // [qg][32 q][66] = 16896 B
    float* redl = (float*)(smem + 16896);    // [qg*2+kh][32 q] = 512 B
    if (l31 == 0) {
#pragma unroll
        for (int r = 0; r < 16; ++r) {
            int q = (r & 3) + 8 * (r >> 2) + 4 * half;
            redl[(qg * 2 + kh) * 32 + q] = lacc[r];
        }
    }
    if (kh == 1) {
        float* Bo = redO + qg * 32 * 66;
#pragma unroll
        for (int r = 0; r < 16; ++r) {
            int q = (r & 3) + 8 * (r >> 2) + 4 * half;
            Bo[q * 66 + l31] = O0[r];
            Bo[q * 66 + 32 + l31] = O1[r];
        }
    }
    __syncthreads();
    if (kh == 0) {
        const float* Bo = redO + qg * 32 * 66;
#pragma unroll
        for (int r = 0; r < 16; ++r) {
            int q = (r & 3) + 8 * (r >> 2) + 4 * half;
            float o0 = O0[r] + Bo[q * 66 + l31];
            float o1 = O1[r] + Bo[q * 66 + 32 + l31];
            float inv = 1.f / (redl[(qg * 2 + 0) * 32 + q] + redl[(qg * 2 + 1) * 32 + q]);
            size_t row = (size_t)(b * 4096 + qt * 64 + qg * 32 + q);
            short* d = xbb + row * 512 + h * 64 + l31;
            d[0] = f2bf(o0 * inv);
            d[32] = f2bf(o1 * inv);
        }
    }
}

// ---------------------------------------------------------------------------
extern "C" void kernel_launch(void* const* d_in, const int* in_sizes, int n_in,
                              void* d_out, int out_size, void* d_ws, size_t ws_size,
                              hipStream_t stream)
{
    const float* query = (const float*)d_in[0];
    const float* key   = (const float*)d_in[1];
    const float* value = (const float*)d_in[2];
    const float* Wq1   = (const float*)d_in[3];
    const float* bq1   = (const float*)d_in[4];
    const float* Wq2   = (const float*)d_in[5];
    const float* bq2   = (const float*)d_in[6];
    const float* Wk1   = (const float*)d_in[7];
    const float* bk1   = (const float*)d_in[8];
    const float* Wk2   = (const float*)d_in[9];
    const float* bk2   = (const float*)d_in[10];
    const float* Wv    = (const float*)d_in[11];
    const float* bv    = (const float*)d_in[12];
    const float* Wo    = (const float*)d_in[13];
    const float* bo    = (const float*)d_in[14];
    float* out = (float*)d_out;

    // Workspace (bytes), overlays (proven R13):
    char* ws = (char*)d_ws;
    short* H1q   = (short*)(ws + 0);
    short* H1k   = (short*)(ws + 16777216);
    short* xbb   = (short*)(ws + 0);
    short* qcast = (short*)(ws + 33554432);
    short* kcast = (short*)(ws + 41943040);
    short* vcast = (short*)(ws + 50331648);
    short* qbb   = (short*)(ws + 33554432);
    short* kbb   = (short*)(ws + 37748736);
    short* vbb   = (short*)(ws + 41943040);
    short* kfr   = (short*)(ws + 50331648);
    short* vfr   = (short*)(ws + 54525952);
    short* Wq1t  = (short*)(ws + 62914560);
    short* Wk1t  = (short*)(ws + 63963136);
    short* Wq2t  = (short*)(ws + 65011712);
    short* Wk2t  = (short*)(ws + 65536000);
    short* Wvt   = (short*)(ws + 66060288);
    short* Wot   = (short*)(ws + 66584576);   // 512 KB -> end 67,108,864

    dim3 blk(256);
    const float qscale = 0.17677669529663687f * 1.4426950408889634f;

    // fused input casts + weight prep (one dispatch)
    prep_all<<<dim3(8192), blk, 0, stream>>>(
        query, key, value, qcast, kcast, vcast,
        Wq1, Wk1, Wq2, Wk2, Wv, Wo, Wq1t, Wk1t, Wq2t, Wk2t, Wvt, Wot);

    // MLP layer 1 (q & k batched): GELU, bf16. N=1024, K=512, BM=128, BN=128
    gemm_bt<1, 0, 128, 128><<<dim3(8 * 64, 1, 2), blk, 0, stream>>>(
        qcast, kcast, Wq1t, Wk1t, bq1, bk1, H1q, H1k, 1.f, 1.f, 8, 1024, 512);
    // MLP layer 2 (q & k batched): q pre-scaled. N=256, K=1024, BM=64, BN=64
    gemm_bt<0, 0, 64, 64><<<dim3(4 * 128, 1, 2), blk, 0, stream>>>(
        H1q, H1k, Wq2t, Wk2t, bq2, bk2, qbb, kbb, qscale, 1.f, 4, 256, 1024);
    // v projection: N=512, K=512, BM=64, BN=64
    gemm_bt<0, 0, 64, 64><<<dim3(8 * 128, 1, 1), blk, 0, stream>>>(
        vcast, vcast, Wvt, Wvt, bv, bv, vbb, vbb, 1.f, 1.f, 8, 512, 512);
    // fused frag-major repacks (one dispatch)
    repack_kv<<<dim3(64, 32), blk, 0, stream>>>(kbb, kfr, vbb, vfr);
    // attention: R13 proven flash
    flash_ks<<<dim3(1024), blk, 0, stream>>>(qbb, kfr, vfr, xbb);
    // output projection: N=512, K=512, BM=64, BN=64 -> f32
    gemm_bt<0, 1, 64, 64><<<dim3(8 * 128, 1, 1), blk, 0, stream>>>(
        xbb, xbb, Wot, Wot, bo, bo, out, out, 1.f, 1.f, 8, 512, 512);
}